// Round 7
// baseline (389.165 us; speedup 1.0000x reference)
//
#include <hip/hip_runtime.h>
#include <hip/hip_cooperative_groups.h>
#include <stdint.h>

namespace cg = cooperative_groups;

typedef unsigned long long u64;
typedef unsigned int u32;
typedef unsigned short u16;
typedef u32 u32x4 __attribute__((ext_vector_type(4)));
typedef float f32x4 __attribute__((ext_vector_type(4)));
typedef int i32x4 __attribute__((ext_vector_type(4)));
typedef int i32x2 __attribute__((ext_vector_type(2)));

// Fixed problem shape (N=100000, E=1600000, C_IN=C_OUT=128, NHEADS=4)
#define CIN 128
#define NN 100000
#define EE 1600000

__device__ __forceinline__ float bf2f(u16 v) {
    union { u32 u; float f; } cv;
    cv.u = ((u32)v) << 16;
    return cv.f;
}

__device__ __forceinline__ u16 f2bf(float f) {      // RNE f32 -> bf16
    u32 b = __float_as_uint(f);
    return (u16)((b + 0x7FFFu + ((b >> 16) & 1u)) >> 16);
}

// Order-preserving bf16 -> u16 map (sign-flip trick). Key layout (64b):
//   [63:48] mono16(s_i)   — score, max wins
//   [47:27] 0x1FFFFF - e  — tie: min edge id wins (E < 2^21)
//   [26:10] dst           — payload only (compared only when score+e equal
//                           => same edge => equal keys)
//   [9:0]   0
// Same ordering as the original mono32(s_j+s_i)<<32 | ~e key within a src
// group (s_j const per group; f32 add of two bf16s exact; ties identical).
// inv_e > 0 => key never 0 => 0 means "empty slot".
__device__ __forceinline__ u16 mono16(u16 b) {
    return (b & 0x8000u) ? (u16)~b : (u16)(b | 0x8000u);
}

// ---------------------------------------------------------------------------
// k_s: zero seg / nm; V table (W ⊗ att_i) in LDS; mono16(s_i) per node.
// FMA order per node bit-identical to all passing rounds.
__global__ __launch_bounds__(256, 4) void k_s(const u16* __restrict__ x,
                                              const u16* __restrict__ W,
                                              const u16* __restrict__ att,
                                              ushort4* __restrict__ sib,
                                              u32x4* __restrict__ seg16, int n_seg16,
                                              int* __restrict__ nm, int n_nodes) {
    int stride = gridDim.x * blockDim.x;
    int tid = blockIdx.x * blockDim.x + threadIdx.x;
    u32x4 z = { 0, 0, 0, 0 };
    for (int i = tid; i < n_seg16; i += stride) __builtin_nontemporal_store(z, &seg16[i]);
    for (int i = tid; i < n_nodes; i += stride) nm[i] = 0;

    // ---- V table in LDS (f32), w_i half only ----
    __shared__ float Vl[512];
    for (int slot = threadIdx.x; slot < 512; slot += 256) {
        int k = slot >> 2, head = slot & 3;
        float acc = 0.0f;
        #pragma unroll
        for (int c = 0; c < 32; ++c)
            acc += bf2f(W[k * CIN + head * 32 + c]) * bf2f(att[head * 64 + 32 + c]);
        Vl[slot] = acc;
    }
    __syncthreads();

    for (int n = tid; n < n_nodes; n += stride) {
        const uint4* row = (const uint4*)(x + (size_t)n * CIN);
        float acc[4];
        #pragma unroll
        for (int h = 0; h < 4; ++h) acc[h] = 0.0f;
        #pragma unroll 4
        for (int q = 0; q < 16; ++q) {
            uint4 v = row[q];
            u32 w[4] = { v.x, v.y, v.z, v.w };
            #pragma unroll
            for (int j = 0; j < 4; ++j) {
                float x0 = bf2f((u16)(w[j] & 0xFFFFu));
                float x1 = bf2f((u16)(w[j] >> 16));
                int k0 = q * 8 + j * 2;
                #pragma unroll
                for (int h = 0; h < 4; ++h) acc[h] += x0 * Vl[k0 * 4 + h];
                #pragma unroll
                for (int h = 0; h < 4; ++h) acc[h] += x1 * Vl[(k0 + 1) * 4 + h];
            }
        }
        ushort4 a;
        a.x = mono16(f2bf(acc[0])); a.y = mono16(f2bf(acc[1]));
        a.z = mono16(f2bf(acc[2])); a.w = mono16(f2bf(acc[3]));
        sib[n] = a;
    }
}

// ---------------------------------------------------------------------------
// Test-then-atomic, 2 edges/thread. Full test->atomic block per edge (r2's
// 4-wide with all-upfront tests doubled admissions; 2-wide keeps in-flight
// edges at ~1M, mild). int2-vectorized NT ei loads; x_out zero prologue
// rides the idle write BW (r5: +3µs for 51.2 MB). dst packed in key.
__global__ __launch_bounds__(256) void k_edge(const int* __restrict__ ei,
                                              const ushort4* __restrict__ sib,
                                              u64* __restrict__ seg,
                                              u32x4* __restrict__ xout16, int n_xout16,
                                              int n_edges) {
    int t = blockIdx.x * blockDim.x + threadIdx.x;
    int stride = gridDim.x * blockDim.x;
    u32x4 z = { 0, 0, 0, 0 };
    for (int i = t; i < n_xout16; i += stride) __builtin_nontemporal_store(z, &xout16[i]);

    int e0 = 2 * t;
    if (e0 >= n_edges) return;
    i32x2 s2 = __builtin_nontemporal_load(((const i32x2*)ei) + t);
    i32x2 d2 = __builtin_nontemporal_load(((const i32x2*)(ei + n_edges)) + t);
    ushort4 m0 = sib[d2.x];
    ushort4 m1 = sib[d2.y];
    u64* r0 = seg + (size_t)s2.x * 4;
    u64* r1 = seg + (size_t)s2.y * 4;

    {   // edge e0
        ulonglong2 c01 = *(const ulonglong2*)(r0);
        ulonglong2 c23 = *(const ulonglong2*)(r0 + 2);
        u64 lo = ((u64)(0x1FFFFFu - (u32)e0) << 27) | ((u64)(u32)d2.x << 10);
        u64 k0 = ((u64)m0.x << 48) | lo;
        u64 k1 = ((u64)m0.y << 48) | lo;
        u64 k2 = ((u64)m0.z << 48) | lo;
        u64 k3 = ((u64)m0.w << 48) | lo;
        if (k0 > c01.x) atomicMax(&r0[0], k0);
        if (k1 > c01.y) atomicMax(&r0[1], k1);
        if (k2 > c23.x) atomicMax(&r0[2], k2);
        if (k3 > c23.y) atomicMax(&r0[3], k3);
    }
    {   // edge e0+1
        ulonglong2 c01 = *(const ulonglong2*)(r1);
        ulonglong2 c23 = *(const ulonglong2*)(r1 + 2);
        u64 lo = ((u64)(0x1FFFFFu - (u32)(e0 + 1)) << 27) | ((u64)(u32)d2.y << 10);
        u64 k0 = ((u64)m1.x << 48) | lo;
        u64 k1 = ((u64)m1.y << 48) | lo;
        u64 k2 = ((u64)m1.z << 48) | lo;
        u64 k3 = ((u64)m1.w << 48) | lo;
        if (k0 > c01.x) atomicMax(&r1[0], k0);
        if (k1 > c01.y) atomicMax(&r1[1], k1);
        if (k2 > c23.x) atomicMax(&r1[2], k2);
        if (k3 > c23.y) atomicMax(&r1[3], k3);
    }
}

// ---------------------------------------------------------------------------
// Merged select+final (cooperative): phase 1 decodes winner dst from each
// seg key -> nm; grid.sync(); phase 2 = edge_keep + node_mask + slices.
// Grid 1563x256 = 400128 covers both phases (N4 = E/4 = 400000); 7 blocks/CU
// co-resident (28 waves/CU <= 32). Saves one dispatch + launch gap.
__global__ __launch_bounds__(256) void k_sf(const int* __restrict__ ei,
                                            const u64* __restrict__ seg,
                                            int* nm,
                                            const int* __restrict__ slices,
                                            float* __restrict__ out,
                                            int n4, int n_edges, int n_nodes,
                                            int ek_off, int nm_off, int sl_off) {
    int t = blockIdx.x * blockDim.x + threadIdx.x;
    if (t < n4) {
        u64 m = seg[t];
        if (m) nm[(int)((m >> 10) & 0x1FFFFu)] = 1;   // race-benign: all store 1
    }
    cg::this_grid().sync();
    if (4 * t < n_edges) {
        i32x4 srcs = __builtin_nontemporal_load(((const i32x4*)ei) + t);
        i32x4 dsts = __builtin_nontemporal_load(((const i32x4*)(ei + n_edges)) + t);
        f32x4 v;
        v.x = (nm[srcs.x] & nm[dsts.x]) ? 1.0f : 0.0f;
        v.y = (nm[srcs.y] & nm[dsts.y]) ? 1.0f : 0.0f;
        v.z = (nm[srcs.z] & nm[dsts.z]) ? 1.0f : 0.0f;
        v.w = (nm[srcs.w] & nm[dsts.w]) ? 1.0f : 0.0f;
        __builtin_nontemporal_store(v, &((f32x4*)(out + ek_off))[t]);
    }
    if (t < n_nodes) out[nm_off + t] = nm[t] ? 1.0f : 0.0f;
    if (t < 2) out[sl_off + t] = (float)slices[t];   // 0 and 100000, exact
}

// ---------------------------------------------------------------------------
extern "C" void kernel_launch(void* const* d_in, const int* in_sizes, int n_in,
                              void* d_out, int out_size, void* d_ws, size_t ws_size,
                              hipStream_t stream) {
    // Bind inputs by UNIQUE flat size (permutation-proof):
    const u16* x = nullptr; const int* ei = nullptr; const int* sl = nullptr;
    const u16* W = nullptr; const u16* att = nullptr;
    for (int i = 0; i < n_in; ++i) {
        switch (in_sizes[i]) {
            case NN * CIN:   x   = (const u16*)d_in[i]; break;
            case 2 * EE:     ei  = (const int*)d_in[i]; break;
            case 2:          sl  = (const int*)d_in[i]; break;
            case CIN * CIN:  W   = (const u16*)d_in[i]; break;
            case 256:        att = (const u16*)d_in[i]; break;
            default: break;
        }
    }
    if (!x || !ei || !sl || !W || !att) return;

    float* out = (float*)d_out;             // f32 concat, return order
    const int N = NN;
    const int E = EE;
    int N4 = N * 4;

    // output layout (f32): [x_out N*128][edge_keep E][node_mask N][slices 2]
    int ek_off = N * CIN;
    int nm_off = ek_off + E;
    int sl_off = nm_off + N;

    // workspace (16B-aligned): sib N*8 | nm N*4 | seg N4*8  (4.4 MB)
    char* ws = (char*)d_ws;
    ushort4* sib = (ushort4*)(ws);
    int*     nm  = (int*)    (ws + (size_t)N * 8);
    u64*     seg = (u64*)    (ws + (size_t)N * 12);

    const int n_xout16 = N * CIN / 4;        // u32x4 count, f32 x_out region
    const int n_seg16  = N4 / 2;             // u32x4 count, seg table

    k_s<<<1280, 256, 0, stream>>>(x, W, att, sib,
                                  (u32x4*)seg, n_seg16, nm, N);
    k_edge<<<(E / 2 + 255) / 256, 256, 0, stream>>>(ei, sib, seg,
                                                    (u32x4*)out, n_xout16, E);

    int n_edges = E, n_nodes = N;
    void* args[] = { (void*)&ei, (void*)&seg, (void*)&nm, (void*)&sl, (void*)&out,
                     (void*)&N4, (void*)&n_edges, (void*)&n_nodes,
                     (void*)&ek_off, (void*)&nm_off, (void*)&sl_off };
    hipLaunchCooperativeKernel((const void*)k_sf, dim3((N4 + 255) / 256), dim3(256),
                               args, 0, stream);
}

// Round 8
// 197.386 us; speedup vs baseline: 1.9716x; 1.9716x over previous
//
#include <hip/hip_runtime.h>
#include <stdint.h>

typedef unsigned long long u64;
typedef unsigned int u32;
typedef unsigned short u16;
typedef u32 u32x4 __attribute__((ext_vector_type(4)));
typedef float f32x4 __attribute__((ext_vector_type(4)));
typedef int i32x4 __attribute__((ext_vector_type(4)));

// Fixed problem shape (N=100000, E=1600000, C_IN=C_OUT=128, NHEADS=4)
#define CIN 128
#define NN 100000
#define EE 1600000

__device__ __forceinline__ float bf2f(u16 v) {
    union { u32 u; float f; } cv;
    cv.u = ((u32)v) << 16;
    return cv.f;
}

__device__ __forceinline__ u16 f2bf(float f) {      // RNE f32 -> bf16
    u32 b = __float_as_uint(f);
    return (u16)((b + 0x7FFFu + ((b >> 16) & 1u)) >> 16);
}

// Order-preserving bf16 -> u16 map (sign-flip trick). Key layout (64b):
//   [63:48] mono16(s_i)   — score, max wins
//   [47:27] 0x1FFFFF - e  — tie: min edge id wins (E < 2^21)
//   [26:10] dst           — payload only (compared only when score+e equal
//                           => same edge => equal keys)
//   [9:0]   0
// Same ordering as the original mono32(s_j+s_i)<<32 | ~e key within a src
// group (s_j const per group; f32 add of two bf16s exact; ties identical).
// inv_e > 0 => key never 0 => 0 means "empty slot".
__device__ __forceinline__ u16 mono16(u16 b) {
    return (b & 0x8000u) ? (u16)~b : (u16)(b | 0x8000u);
}

// ---------------------------------------------------------------------------
// k_s: zero seg / nm; V table (W ⊗ att_i) in LDS; mono16(s_i) per node.
// FMA order per node bit-identical to all passing rounds.
__global__ __launch_bounds__(256, 4) void k_s(const u16* __restrict__ x,
                                              const u16* __restrict__ W,
                                              const u16* __restrict__ att,
                                              ushort4* __restrict__ sib,
                                              u32x4* __restrict__ seg16, int n_seg16,
                                              int* __restrict__ nm, int n_nodes) {
    int stride = gridDim.x * blockDim.x;
    int tid = blockIdx.x * blockDim.x + threadIdx.x;
    u32x4 z = { 0, 0, 0, 0 };
    for (int i = tid; i < n_seg16; i += stride) __builtin_nontemporal_store(z, &seg16[i]);
    for (int i = tid; i < n_nodes; i += stride) nm[i] = 0;

    // ---- V table in LDS (f32), w_i half only ----
    __shared__ float Vl[512];
    for (int slot = threadIdx.x; slot < 512; slot += 256) {
        int k = slot >> 2, head = slot & 3;
        float acc = 0.0f;
        #pragma unroll
        for (int c = 0; c < 32; ++c)
            acc += bf2f(W[k * CIN + head * 32 + c]) * bf2f(att[head * 64 + 32 + c]);
        Vl[slot] = acc;
    }
    __syncthreads();

    for (int n = tid; n < n_nodes; n += stride) {
        const uint4* row = (const uint4*)(x + (size_t)n * CIN);
        float acc[4];
        #pragma unroll
        for (int h = 0; h < 4; ++h) acc[h] = 0.0f;
        #pragma unroll 4
        for (int q = 0; q < 16; ++q) {
            uint4 v = row[q];
            u32 w[4] = { v.x, v.y, v.z, v.w };
            #pragma unroll
            for (int j = 0; j < 4; ++j) {
                float x0 = bf2f((u16)(w[j] & 0xFFFFu));
                float x1 = bf2f((u16)(w[j] >> 16));
                int k0 = q * 8 + j * 2;
                #pragma unroll
                for (int h = 0; h < 4; ++h) acc[h] += x0 * Vl[k0 * 4 + h];
                #pragma unroll
                for (int h = 0; h < 4; ++h) acc[h] += x1 * Vl[(k0 + 1) * 4 + h];
            }
        }
        ushort4 a;
        a.x = mono16(f2bf(acc[0])); a.y = mono16(f2bf(acc[1]));
        a.z = mono16(f2bf(acc[2])); a.w = mono16(f2bf(acc[3]));
        sib[n] = a;
    }
}

// ---------------------------------------------------------------------------
// Test-then-atomic single pass, 1 edge/thread (proven best: ~775K admissions
// near the online floor; 2-wide neutral-at-best r7, 4-wide regressed r2,
// no-test regressed r3, offline filter failed r4). NT loads for the one-shot
// ei stream keep per-XCD L2 for sib + seg lines. dst packed into the key ->
// k_select needs no ei gather. x_out zero prologue rides the idle write BW
// (r5: +3µs for 51.2 MB, frees k_s by more).
__global__ __launch_bounds__(256) void k_edge(const int* __restrict__ ei,
                                              const ushort4* __restrict__ sib,
                                              u64* __restrict__ seg,
                                              u32x4* __restrict__ xout16, int n_xout16,
                                              int n_edges) {
    int t = blockIdx.x * blockDim.x + threadIdx.x;
    int stride = gridDim.x * blockDim.x;
    u32x4 z = { 0, 0, 0, 0 };
    for (int i = t; i < n_xout16; i += stride) __builtin_nontemporal_store(z, &xout16[i]);

    int e = t;
    if (e >= n_edges) return;
    int src = __builtin_nontemporal_load(ei + e);
    int dst = __builtin_nontemporal_load(ei + n_edges + e);
    ushort4 m = sib[dst];
    u64 lo = ((u64)(0x1FFFFFu - (u32)e) << 27) | ((u64)(u32)dst << 10);
    u64* r = seg + (size_t)src * 4;
    ulonglong2 c01 = *(const ulonglong2*)(r);
    ulonglong2 c23 = *(const ulonglong2*)(r + 2);
    u64 k0 = ((u64)m.x << 48) | lo;
    u64 k1 = ((u64)m.y << 48) | lo;
    u64 k2 = ((u64)m.z << 48) | lo;
    u64 k3 = ((u64)m.w << 48) | lo;
    if (k0 > c01.x) atomicMax(&r[0], k0);
    if (k1 > c01.y) atomicMax(&r[1], k1);
    if (k2 > c23.x) atomicMax(&r[2], k2);
    if (k3 > c23.y) atomicMax(&r[3], k3);
}

// ---------------------------------------------------------------------------
// Decode winner dst straight from the key (no ei gather): coalesced 3.2 MB
// stream + scattered nm stores. Race-benign: all writers store 1.
__global__ void k_select(const u64* __restrict__ seg,
                         int* __restrict__ nm, int n4) {
    int t = blockIdx.x * blockDim.x + threadIdx.x;
    if (t >= n4) return;
    u64 m = seg[t];
    if (m) nm[(int)((m >> 10) & 0x1FFFFu)] = 1;
}

// ---------------------------------------------------------------------------
// Fused epilogue: edge_keep (4 edges/thread, nontemporal f32x4) + node_mask
// f32 + batch_slices f32.
__global__ void k_final(const int* __restrict__ ei, const int* __restrict__ nm,
                        const int* __restrict__ slices, float* __restrict__ out,
                        int n_edges, int n_nodes, int ek_off, int nm_off, int sl_off) {
    int t = blockIdx.x * blockDim.x + threadIdx.x;
    int e0 = 4 * t;
    if (e0 < n_edges) {
        i32x4 srcs = __builtin_nontemporal_load(((const i32x4*)ei) + t);
        i32x4 dsts = __builtin_nontemporal_load(((const i32x4*)(ei + n_edges)) + t);
        f32x4 v;
        v.x = (nm[srcs.x] & nm[dsts.x]) ? 1.0f : 0.0f;
        v.y = (nm[srcs.y] & nm[dsts.y]) ? 1.0f : 0.0f;
        v.z = (nm[srcs.z] & nm[dsts.z]) ? 1.0f : 0.0f;
        v.w = (nm[srcs.w] & nm[dsts.w]) ? 1.0f : 0.0f;
        __builtin_nontemporal_store(v, &((f32x4*)(out + ek_off))[t]);
    }
    if (t < n_nodes) out[nm_off + t] = nm[t] ? 1.0f : 0.0f;
    if (t < 2) out[sl_off + t] = (float)slices[t];   // 0 and 100000, exact
}

// ---------------------------------------------------------------------------
extern "C" void kernel_launch(void* const* d_in, const int* in_sizes, int n_in,
                              void* d_out, int out_size, void* d_ws, size_t ws_size,
                              hipStream_t stream) {
    // Bind inputs by UNIQUE flat size (permutation-proof):
    const u16* x = nullptr; const int* ei = nullptr; const int* sl = nullptr;
    const u16* W = nullptr; const u16* att = nullptr;
    for (int i = 0; i < n_in; ++i) {
        switch (in_sizes[i]) {
            case NN * CIN:   x   = (const u16*)d_in[i]; break;
            case 2 * EE:     ei  = (const int*)d_in[i]; break;
            case 2:          sl  = (const int*)d_in[i]; break;
            case CIN * CIN:  W   = (const u16*)d_in[i]; break;
            case 256:        att = (const u16*)d_in[i]; break;
            default: break;
        }
    }
    if (!x || !ei || !sl || !W || !att) return;

    float* out = (float*)d_out;             // f32 concat, return order
    const int N = NN;
    const int E = EE;
    const int N4 = N * 4;

    // output layout (f32): [x_out N*128][edge_keep E][node_mask N][slices 2]
    const int ek_off = N * CIN;
    const int nm_off = ek_off + E;
    const int sl_off = nm_off + N;

    // workspace (16B-aligned): sib N*8 | nm N*4 | seg N4*8  (4.4 MB)
    char* ws = (char*)d_ws;
    ushort4* sib = (ushort4*)(ws);
    int*     nm  = (int*)    (ws + (size_t)N * 8);
    u64*     seg = (u64*)    (ws + (size_t)N * 12);

    const int n_xout16 = N * CIN / 4;        // u32x4 count, f32 x_out region
    const int n_seg16  = N4 / 2;             // u32x4 count, seg table

    k_s<<<1280, 256, 0, stream>>>(x, W, att, sib,
                                  (u32x4*)seg, n_seg16, nm, N);
    k_edge<<<(E + 255) / 256, 256, 0, stream>>>(ei, sib, seg,
                                                (u32x4*)out, n_xout16, E);
    k_select<<<(N4 + 255) / 256, 256, 0, stream>>>(seg, nm, N4);
    k_final<<<(E / 4 + 255) / 256, 256, 0, stream>>>(ei, nm, sl, out, E, N, ek_off, nm_off, sl_off);
}